// Round 13
// baseline (140.017 us; speedup 1.0000x reference)
//
#include <hip/hip_runtime.h>
#include <hip/hip_bf16.h>

#define NPTS 2048
#define LOG2E 1.4426950408889634f
#define NJC 16     // chamfer j-chunks
#define JCH 128    // points per chunk
#define KSPLIT 8

typedef short bf16x8 __attribute__((ext_vector_type(8)));
typedef float f32x4 __attribute__((ext_vector_type(4)));
typedef unsigned uint32x4 __attribute__((ext_vector_type(4)));
typedef __attribute__((address_space(3))) char lds_char;
typedef __attribute__((address_space(1))) const char glob_char;

union PBU { uint32x4 u; bf16x8 v; };

static __device__ __forceinline__ unsigned cvt_pk_bf16(float a, float b) {
    unsigned r;
    asm("v_cvt_pk_bf16_f32 %0, %1, %2" : "=v"(r) : "v"(a), "v"(b));
    return r;
}
static __device__ __forceinline__ float b2f(unsigned short u) {
    return __uint_as_float((unsigned)u << 16);
}

// ---------------------------------------------------------------------------
// K0 (fused): blocks 0..255 -> xT tiles; blocks 256..259 -> weight casts +
// chamfer ticket-counter zeroing.
// ---------------------------------------------------------------------------
__global__ __launch_bounds__(256) void prep_all(const float* __restrict__ xs,
                                                const float* __restrict__ gamma,
                                                const float* __restrict__ beta,
                                                const float* __restrict__ q_w,
                                                const float* __restrict__ kv_w,
                                                const float* __restrict__ proj_w,
                                                __hip_bfloat16* __restrict__ xT,
                                                __hip_bfloat16* __restrict__ Wpb,
                                                __hip_bfloat16* __restrict__ Wb,
                                                unsigned* __restrict__ counter) {
    const int bid = blockIdx.x;
    const int t = threadIdx.x;
    if (bid < 256) {
        const int fr = bid >> 5;           // b*4 + f
        const int n0 = (bid & 31) * 64;
        const float* __restrict__ A = xs + (size_t)fr * 64 * NPTS;   // [c][n]

        __shared__ float As[64][68];
        __shared__ float sg[64], sb[64];

        if (t < 64) {
            const float inv = 1.0f / sqrtf(1.0f + 1e-5f);
            sg[t] = gamma[t] * inv;
            sb[t] = beta[t];
        }
        const int tx = t & 15, ty = t >> 4;
        for (int r = 0; r < 4; ++r) {
            int row = ty + 16 * r, col = tx * 4;
            *(float4*)&As[row][col] = *(const float4*)&A[(size_t)row * NPTS + n0 + col];
        }
        __syncthreads();

        const int nl = t >> 2, c0 = (t & 3) * 16;
        bf16x8 v0, v1;
#pragma unroll
        for (int j = 0; j < 8; ++j) {
            float a = As[c0 + j][nl] * sg[c0 + j] + sb[c0 + j];
            v0[j] = (short)__bfloat16_as_ushort(__float2bfloat16(a));
        }
#pragma unroll
        for (int j = 0; j < 8; ++j) {
            float a = As[c0 + 8 + j][nl] * sg[c0 + 8 + j] + sb[c0 + 8 + j];
            v1[j] = (short)__bfloat16_as_ushort(__float2bfloat16(a));
        }
        __hip_bfloat16* dst = xT + ((size_t)fr * NPTS + n0 + nl) * 64 + c0;
        *(bf16x8*)(dst) = v0;
        *(bf16x8*)(dst + 8) = v1;
    } else {
        const int row = (bid - 256) * 256 + t;   // 0..1023
        if (row < 768) {
            const float* src;
            float scale;
            if (row < 256) { src = q_w + row * 64;          scale = 0.125f * LOG2E; }
            else           { src = kv_w + (row - 256) * 64; scale = 1.0f; }
            for (int c = 0; c < 64; ++c)
                Wpb[row * 64 + c] = __float2bfloat16(src[c] * scale);
        } else if (row < 832) {
            const int j = row - 768;
            for (int c = 0; c < 64; ++c)
                Wb[j * 64 + c] = __float2bfloat16(proj_w[j * 64 + c]);
        } else if (row == 1023) {
            *counter = 0;          // chamfer ticket counter, zeroed every call
        }
    }
}

// ---------------------------------------------------------------------------
// K1: QKV via MFMA, zero LDS (verified round-9 version).
// ---------------------------------------------------------------------------
__global__ __launch_bounds__(256) void qkv_mfma(const __hip_bfloat16* __restrict__ xT,
                                                const __hip_bfloat16* __restrict__ Wpb,
                                                __hip_bfloat16* __restrict__ Qg,
                                                __hip_bfloat16* __restrict__ Kg,
                                                __hip_bfloat16* __restrict__ Vtg) {
    const int bf = blockIdx.z;            // b*2 + f01
    const int b = bf >> 1, f01 = bf & 1;
    const int jt = blockIdx.y;            // 0..11
    const int f_src = (jt < 4) ? f01 : (3 - f01);
    const int n0 = blockIdx.x * 64;

    const int t = threadIdx.x, lane = t & 63, w = t >> 6;
    const int l15 = lane & 15, g = (lane >> 4) & 3;

    const __hip_bfloat16* __restrict__ xfb = xT + (size_t)(b * 4 + f_src) * NPTS * 64;

    if (jt < 8) {
        const __hip_bfloat16* wp = Wpb + (size_t)(jt * 64 + w * 16 + l15) * 64 + g * 8;
        bf16x8 wf0 = *(const bf16x8*)(wp);
        bf16x8 wf1 = *(const bf16x8*)(wp + 32);
        __hip_bfloat16* __restrict__ dst = (jt < 4 ? Qg : Kg) + (size_t)bf * NPTS * 256;
        const int jb = (jt & 3) * 64 + w * 16 + g * 4;
#pragma unroll
        for (int nt = 0; nt < 4; ++nt) {
            const __hip_bfloat16* xp = xfb + (size_t)(n0 + nt * 16 + l15) * 64 + g * 8;
            bf16x8 xf0 = *(const bf16x8*)(xp);
            bf16x8 xf1 = *(const bf16x8*)(xp + 32);
            f32x4 d = (f32x4){0.f, 0.f, 0.f, 0.f};
            d = __builtin_amdgcn_mfma_f32_16x16x32_bf16(wf0, xf0, d, 0, 0, 0);
            d = __builtin_amdgcn_mfma_f32_16x16x32_bf16(wf1, xf1, d, 0, 0, 0);
            uint2 pv;
            pv.x = cvt_pk_bf16(d[0], d[1]);
            pv.y = cvt_pk_bf16(d[2], d[3]);
            *(uint2*)&dst[(size_t)(n0 + nt * 16 + l15) * 256 + jb] = pv;
        }
    } else {
        const __hip_bfloat16* xp = xfb + (size_t)(n0 + w * 16 + l15) * 64 + g * 8;
        bf16x8 xf0 = *(const bf16x8*)(xp);
        bf16x8 xf1 = *(const bf16x8*)(xp + 32);
        __hip_bfloat16* __restrict__ dst = Vtg + (size_t)bf * 256 * NPTS;
#pragma unroll
        for (int tj = 0; tj < 4; ++tj) {
            const int ch = (jt - 8) * 64 + tj * 16 + l15;
            const __hip_bfloat16* wp = Wpb + (size_t)(512 + ch) * 64 + g * 8;
            bf16x8 wf0 = *(const bf16x8*)(wp);
            bf16x8 wf1 = *(const bf16x8*)(wp + 32);
            f32x4 d = (f32x4){0.f, 0.f, 0.f, 0.f};
            d = __builtin_amdgcn_mfma_f32_16x16x32_bf16(xf0, wf0, d, 0, 0, 0);
            d = __builtin_amdgcn_mfma_f32_16x16x32_bf16(xf1, wf1, d, 0, 0, 0);
            uint2 pv;
            pv.x = cvt_pk_bf16(d[0], d[1]);
            pv.y = cvt_pk_bf16(d[2], d[3]);
            *(uint2*)&dst[(size_t)ch * NPTS + n0 + w * 16 + g * 4] = pv;
        }
    }
}

// ---------------------------------------------------------------------------
// K2: MFMA flash attention — 8 waves / 512 threads, 256 q rows per block
// (32 q per wave, 2 q-frags — verified per-wave program).  nblk=8 halves
// the L2 staging redundancy; 4 blocks/CU = 32 waves/CU (max occupancy).
// Staging: waves 0-3 stage K (1 load each), waves 4-7 stage V (1 load each);
// quad-buffered LDS, prefetch depth 2, one barrier/tile, vmcnt(2)/(1)/(0).
// ---------------------------------------------------------------------------
__global__ __launch_bounds__(512, 8) void attn_mfma(const __hip_bfloat16* __restrict__ Qg,
                                                    const __hip_bfloat16* __restrict__ Kg,
                                                    const __hip_bfloat16* __restrict__ Vtg,
                                                    __hip_bfloat16* __restrict__ OTb,
                                                    float* __restrict__ Lp) {
    const int combo = blockIdx.x;          // bf*4 + h
    const int bf = combo >> 2, h = combo & 3;
    const int n0 = blockIdx.y * 256;
    const int split = blockIdx.z;
    const int kbase = split * (NPTS / KSPLIT);
    const int NT = NPTS / KSPLIT / 32;     // 8 k-tiles of 32 per split

    __shared__ __align__(16) char smem[32768];   // 4 bufs x (K 4KB | V 4KB)

    const int t = threadIdx.x;
    const int lane = t & 63, w = t >> 6;         // w in 0..7
    const int l15 = lane & 15, g = (lane >> 4) & 3;

    // staging role: waves 0-3 stage K rows w*8+srow; waves 4-7 stage V rows (w-4)*16+vsr
    const int srow = lane >> 3, sslot = lane & 7;
    const int vsr = lane >> 2, vslot = lane & 3;
    const int kcs = (sslot ^ srow) * 8;                  // krow&7 == srow
    const int vcs = (vslot ^ ((vsr >> 1) & 3)) * 8;      // (vrow>>1)&3 == (vsr>>1)&3

    // Q B-fragments: wave w covers q rows n0 + w*32 + {0..15, 16..31}
    const __hip_bfloat16* qbase =
        Qg + ((size_t)bf * NPTS + n0 + w * 32 + l15) * 256 + h * 64 + g * 8;
    bf16x8 qf[2][2];
    qf[0][0] = *(const bf16x8*)(qbase);
    qf[0][1] = *(const bf16x8*)(qbase + 32);
    qf[1][0] = *(const bf16x8*)(qbase + 16 * 256);
    qf[1][1] = *(const bf16x8*)(qbase + 16 * 256 + 32);

    const __hip_bfloat16* kgb = Kg + (size_t)bf * NPTS * 256 + h * 64;
    const __hip_bfloat16* vgb = Vtg + ((size_t)bf * 256 + h * 64) * NPTS;

    int koff[2][2], voff[4];
#pragma unroll
    for (int tt = 0; tt < 2; ++tt) {
        const int row = tt * 16 + l15;
#pragma unroll
        for (int s = 0; s < 2; ++s)
            koff[tt][s] = row * 128 + (((s * 4 + g) ^ (row & 7)) << 4);
    }
#pragma unroll
    for (int ct = 0; ct < 4; ++ct) {
        const int row = ct * 16 + l15;
        voff[ct] = 4096 + row * 64 + ((g ^ ((row >> 1) & 3)) << 4);
    }

    f32x4 oacc[2][4];
    float lsum[2] = {0.f, 0.f};
#pragma unroll
    for (int f = 0; f < 2; ++f)
#pragma unroll
        for (int r = 0; r < 4; ++r) oacc[f][r] = (f32x4){0.f, 0.f, 0.f, 0.f};

    auto stage = [&](int kt) {
        const int bsel = kt & 3;
        if (w < 4) {
            // K: rows w*8 + srow (32 rows total), dest linear at w*1024
            const __hip_bfloat16* ksrc =
                kgb + (size_t)(kbase + kt * 32 + w * 8 + srow) * 256 + kcs;
            __builtin_amdgcn_global_load_lds((const glob_char*)ksrc,
                (lds_char*)(smem + bsel * 8192 + w * 1024), 16, 0, 0);
        } else {
            // V: c-rows (w-4)*16 + vsr (64 rows total), dest 4096 + (w-4)*1024
            const __hip_bfloat16* vsrc =
                vgb + (size_t)((w - 4) * 16 + vsr) * NPTS + kbase + kt * 32 + vcs;
            __builtin_amdgcn_global_load_lds((const glob_char*)vsrc,
                (lds_char*)(smem + bsel * 8192 + 4096 + (w - 4) * 1024), 16, 0, 0);
        }
    };

    auto tile = [&](int kt) {
        const char* B = smem + (kt & 3) * 8192;
        bf16x8 kf[2][2];
#pragma unroll
        for (int tt = 0; tt < 2; ++tt)
#pragma unroll
            for (int s = 0; s < 2; ++s)
                kf[tt][s] = *(const bf16x8*)(B + koff[tt][s]);

        bf16x8 pb[2];
#pragma unroll
        for (int f = 0; f < 2; ++f) {
            f32x4 st0 = (f32x4){0.f, 0.f, 0.f, 0.f}, st1 = st0;
            st0 = __builtin_amdgcn_mfma_f32_16x16x32_bf16(kf[0][0], qf[f][0], st0, 0, 0, 0);
            st0 = __builtin_amdgcn_mfma_f32_16x16x32_bf16(kf[0][1], qf[f][1], st0, 0, 0, 0);
            st1 = __builtin_amdgcn_mfma_f32_16x16x32_bf16(kf[1][0], qf[f][0], st1, 0, 0, 0);
            st1 = __builtin_amdgcn_mfma_f32_16x16x32_bf16(kf[1][1], qf[f][1], st1, 0, 0, 0);
            float p00 = __builtin_amdgcn_exp2f(st0[0]);
            float p01 = __builtin_amdgcn_exp2f(st0[1]);
            float p02 = __builtin_amdgcn_exp2f(st0[2]);
            float p03 = __builtin_amdgcn_exp2f(st0[3]);
            float p10 = __builtin_amdgcn_exp2f(st1[0]);
            float p11 = __builtin_amdgcn_exp2f(st1[1]);
            float p12 = __builtin_amdgcn_exp2f(st1[2]);
            float p13 = __builtin_amdgcn_exp2f(st1[3]);
            lsum[f] += ((p00 + p01) + (p02 + p03)) + ((p10 + p11) + (p12 + p13));
            unsigned x0 = cvt_pk_bf16(p00, p01);
            unsigned x1 = cvt_pk_bf16(p02, p03);
            unsigned y0 = cvt_pk_bf16(p10, p11);
            unsigned y1 = cvt_pk_bf16(p12, p13);
            asm("v_permlane32_swap_b32 %0, %1" : "+v"(x0), "+v"(y0));
            asm("v_permlane16_swap_b32 %0, %1" : "+v"(x0), "+v"(y0));
            asm("v_permlane32_swap_b32 %0, %1" : "+v"(x1), "+v"(y1));
            asm("v_permlane16_swap_b32 %0, %1" : "+v"(x1), "+v"(y1));
            PBU pu;
            pu.u = (uint32x4){x0, x1, y0, y1};
            pb[f] = pu.v;
        }

#pragma unroll
        for (int ct = 0; ct < 4; ++ct) {
            bf16x8 vf = *(const bf16x8*)(B + voff[ct]);
            oacc[0][ct] = __builtin_amdgcn_mfma_f32_16x16x32_bf16(vf, pb[0], oacc[0][ct], 0, 0, 0);
            oacc[1][ct] = __builtin_amdgcn_mfma_f32_16x16x32_bf16(vf, pb[1], oacc[1][ct], 0, 0, 0);
        }
    };

    stage(0);
    stage(1);
    for (int kt = 0; kt < NT - 2; ++kt) {
        stage(kt + 2);
        asm volatile("s_waitcnt vmcnt(2)" ::: "memory");
        __builtin_amdgcn_s_barrier();
        asm volatile("" ::: "memory");
        tile(kt);
    }
    asm volatile("s_waitcnt vmcnt(1)" ::: "memory");
    __builtin_amdgcn_s_barrier();
    asm volatile("" ::: "memory");
    tile(NT - 2);
    asm volatile("s_waitcnt vmcnt(0)" ::: "memory");
    __builtin_amdgcn_s_barrier();
    asm volatile("" ::: "memory");
    tile(NT - 1);

    float l0 = lsum[0], l1 = lsum[1];
    l0 += __shfl_xor(l0, 16);
    l0 += __shfl_xor(l0, 32);
    l1 += __shfl_xor(l1, 16);
    l1 += __shfl_xor(l1, 32);
    const int qq = n0 + w * 32 + l15;
    if (lane < 16) {
        Lp[(size_t)(split * 16 + combo) * NPTS + qq] = l0;
        Lp[(size_t)(split * 16 + combo) * NPTS + qq + 16] = l1;
    }

    __hip_bfloat16* __restrict__ Op = OTb + (size_t)(split * 16 + combo) * 64 * NPTS;
#pragma unroll
    for (int ct = 0; ct < 4; ++ct)
#pragma unroll
        for (int r = 0; r < 4; ++r) {
            Op[(size_t)(ct * 16 + g * 4 + r) * NPTS + qq] = __float2bfloat16(oacc[0][ct][r]);
            Op[(size_t)(ct * 16 + g * 4 + r) * NPTS + qq + 16] = __float2bfloat16(oacc[1][ct][r]);
        }
}

// ---------------------------------------------------------------------------
// K3: combine KSPLIT partials + normalize -> Xn bf16 (transposed), MFMA proj,
// bias, xaS f32; frames from xaS.  (verified round-11 version)
// ---------------------------------------------------------------------------
__global__ __launch_bounds__(256) void proj_frames(const __hip_bfloat16* __restrict__ OTb,
                                                   const float* __restrict__ Lp,
                                                   const __hip_bfloat16* __restrict__ Wb,
                                                   const float* __restrict__ proj_b,
                                                   const float* __restrict__ map_w,
                                                   const float* __restrict__ map_b,
                                                   float* __restrict__ out,
                                                   float* __restrict__ frames0) {
    const int bh = blockIdx.y, b = bh >> 2, h = bh & 3;
    const int n0 = blockIdx.x * 64;
    const int cf0 = (b * 2 + 0) * 4 + h;
    const int cf1 = (b * 2 + 1) * 4 + h;

    __shared__ __align__(16) unsigned short Xn[64][72];  // [n][c] bf16
    __shared__ float xaS[64][68];                        // [n][j]

    const int t = threadIdx.x;
    const int lane = t & 63, w = t >> 6;
    const int tx = t & 15, ty = t >> 4;
    const int l15 = lane & 15, g = (lane >> 4) & 3;
    const int nc = n0 + tx * 4;

    float4 L0 = make_float4(0.f, 0.f, 0.f, 0.f), L1 = L0;
#pragma unroll
    for (int s = 0; s < KSPLIT; ++s) {
        float4 a = *(const float4*)&Lp[(size_t)(s * 16 + cf0) * NPTS + nc];
        L0.x += a.x; L0.y += a.y; L0.z += a.z; L0.w += a.w;
        float4 c = *(const float4*)&Lp[(size_t)(s * 16 + cf1) * NPTS + nc];
        L1.x += c.x; L1.y += c.y; L1.z += c.z; L1.w += c.w;
    }
    float4 inv0 = make_float4(1.f / L0.x, 1.f / L0.y, 1.f / L0.z, 1.f / L0.w);
    float4 inv1 = make_float4(1.f / L1.x, 1.f / L1.y, 1.f / L1.z, 1.f / L1.w);

    for (int r = 0; r < 4; ++r) {
        int row = ty + 16 * r, col = tx * 4;   // row = c, col = n_local
        float x0 = 0.f, x1 = 0.f, x2 = 0.f, x3 = 0.f;
        float y0 = 0.f, y1 = 0.f, y2 = 0.f, y3 = 0.f;
#pragma unroll
        for (int s = 0; s < KSPLIT; ++s) {
            ushort4 u0 = *(const ushort4*)&OTb[((size_t)(s * 16 + cf0) * 64 + row) * NPTS + n0 + col];
            ushort4 u1 = *(const ushort4*)&OTb[((size_t)(s * 16 + cf1) * 64 + row) * NPTS + n0 + col];
            x0 += b2f(u0.x); x1 += b2f(u0.y); x2 += b2f(u0.z); x3 += b2f(u0.w);
            y0 += b2f(u1.x); y1 += b2f(u1.y); y2 += b2f(u1.z); y3 += b2f(u1.w);
        }
        Xn[col + 0][row] = __bfloat16_as_ushort(__float2bfloat16(x0 * inv0.x + y0 * inv1.x));
        Xn[col + 1][row] = __bfloat16_as_ushort(__float2bfloat16(x1 * inv0.y + y1 * inv1.y));
        Xn[col + 2][row] = __bfloat16_as_ushort(__float2bfloat16(x2 * inv0.z + y2 * inv1.z));
        Xn[col + 3][row] = __bfloat16_as_ushort(__float2bfloat16(x3 * inv0.w + y3 * inv1.w));
    }
    __syncthreads();

    {
        const __hip_bfloat16* wp = Wb + (size_t)(w * 16 + l15) * 64 + g * 8;
        bf16x8 wf0 = *(const bf16x8*)(wp);
        bf16x8 wf1 = *(const bf16x8*)(wp + 32);
        float pbias[4];
#pragma unroll
        for (int r = 0; r < 4; ++r) pbias[r] = proj_b[w * 16 + g * 4 + r];
#pragma unroll
        for (int nt = 0; nt < 4; ++nt) {
            bf16x8 xf0 = *(const bf16x8*)&Xn[nt * 16 + l15][g * 8];
            bf16x8 xf1 = *(const bf16x8*)&Xn[nt * 16 + l15][g * 8 + 32];
            f32x4 d = (f32x4){0.f, 0.f, 0.f, 0.f};
            d = __builtin_amdgcn_mfma_f32_16x16x32_bf16(wf0, xf0, d, 0, 0, 0);
            d = __builtin_amdgcn_mfma_f32_16x16x32_bf16(wf1, xf1, d, 0, 0, 0);
            float4 v = make_float4(d[0] + pbias[0], d[1] + pbias[1],
                                   d[2] + pbias[2], d[3] + pbias[3]);
            *(float4*)&xaS[nt * 16 + l15][w * 16 + g * 4] = v;
        }
    }
    __syncthreads();

    if (h >= 1) {
        float* __restrict__ xa_out = out + (size_t)(b * 3 + h - 1) * NPTS * 64;
        for (int r = 0; r < 4; ++r) {
            int n = ty + 16 * r;
            float4 v = *(const float4*)&xaS[n][tx * 4];
            *(float4*)&xa_out[(size_t)(n0 + n) * 64 + tx * 4] = v;
        }
    }

    if (t < 192) {
        int r = t / 3, j = t % 3;
        float s = map_b[j];
        for (int c = 0; c < 64; ++c) s += xaS[r][c] * map_w[j * 64 + c];
        int n = n0 + r;
        if (h == 0) frames0[((size_t)b * NPTS + n) * 3 + j] = s;
        else        out[786432 + ((size_t)(b * 3 + h - 1) * NPTS + n) * 3 + j] = s;
    }
}

// ---------------------------------------------------------------------------
// K4a: chamfer partial mins.  grid (NPTS/256, NJC, 4); z = dir*2 + b.
// ---------------------------------------------------------------------------
__global__ __launch_bounds__(256) void chamfer_partial(const float* __restrict__ pc1,
                                                       const float* __restrict__ frames0,
                                                       float* __restrict__ partial) {
    const int z = blockIdx.z;          // dir*2 + b
    const int dir = z >> 1, b = z & 1;
    const int i = blockIdx.x * 256 + threadIdx.x;
    const int j0 = blockIdx.y * JCH;
    const float* __restrict__ px = pc1 + (size_t)b * 3 * NPTS;
    const float* __restrict__ fr = frames0 + (size_t)b * NPTS * 3;

    __shared__ float4 sj[JCH];
    if (threadIdx.x < JCH) {
        int jj = j0 + threadIdx.x;
        float bx = px[jj], by = px[NPTS + jj], bz = px[2 * NPTS + jj];
        if (dir == 1) { bx += fr[jj * 3]; by += fr[jj * 3 + 1]; bz += fr[jj * 3 + 2]; }
        sj[threadIdx.x] = make_float4(bx, by, bz, bx * bx + by * by + bz * bz);
    }
    float ax = px[i], ay = px[NPTS + i], az = px[2 * NPTS + i];
    if (dir == 0) { ax += fr[i * 3]; ay += fr[i * 3 + 1]; az += fr[i * 3 + 2]; }
    const float a2 = ax * ax + ay * ay + az * az;
    __syncthreads();

    float best = 1e30f;
#pragma unroll 4
    for (int k = 0; k < JCH; ++k) {
        float4 p = sj[k];
        float d = a2 + p.w - 2.0f * (ax * p.x + ay * p.y + az * p.z);
        best = fminf(best, d);
    }
    partial[((size_t)z * NJC + blockIdx.y) * NPTS + i] = best;
}

// ---------------------------------------------------------------------------
// K4b (fused): min over chunks + per-block sum; LAST block (device-scope
// ticket) sums the 32 block sums in fixed order -> loss.
// ---------------------------------------------------------------------------
__global__ __launch_bounds__(256) void chamfer_minsum(const float* __restrict__ partial,
                                                      double* __restrict__ sums,
                                                      unsigned* __restrict__ counter,
                                                      float* __restrict__ loss_out) {
    const int gid = blockIdx.x * 256 + threadIdx.x;
    const int z = gid >> 11, i = gid & 2047;
    float best = 1e30f;
#pragma unroll
    for (int c = 0; c < NJC; ++c)
        best = fminf(best, partial[((size_t)z * NJC + c) * NPTS + i]);
    __shared__ double sm[256];
    sm[threadIdx.x] = (double)best;
    __syncthreads();
    for (int off = 128; off > 0; off >>= 1) {
        if (threadIdx.x < off) sm[threadIdx.x] += sm[threadIdx.x + off];
        __syncthreads();
    }
    if (threadIdx.x == 0) {
        sums[blockIdx.x] = sm[0];
        __threadfence();                            // release sums device-wide
        unsigned prev = atomicAdd(counter, 1u);     // device-scope arrival
        if (prev == 31u) {
            __threadfence();                        // acquire others' sums
            double s = 0.0;
            for (int k = 0; k < 32; ++k) s += sums[k];
            loss_out[0] = (float)(s / 4096.0);
            *counter = 0;
        }
    }
}

// ---------------------------------------------------------------------------
extern "C" void kernel_launch(void* const* d_in, const int* in_sizes, int n_in,
                              void* d_out, int out_size, void* d_ws, size_t ws_size,
                              hipStream_t stream) {
    const float* xs     = (const float*)d_in[0];
    const float* pc1    = (const float*)d_in[1];
    // d_in[2] = pc2 (unused by reference)
    const float* gamma  = (const float*)d_in[3];
    const float* beta   = (const float*)d_in[4];
    const float* q_w    = (const float*)d_in[5];
    const float* kv_w   = (const float*)d_in[6];
    const float* proj_w = (const float*)d_in[7];
    const float* proj_b = (const float*)d_in[8];
    const float* map_w  = (const float*)d_in[9];
    const float* map_b  = (const float*)d_in[10];
    float* out = (float*)d_out;

    char* ws = (char*)d_ws;
    __hip_bfloat16* Qg  = (__hip_bfloat16*)(ws);              // 4 MiB
    __hip_bfloat16* Kg  = (__hip_bfloat16*)(ws + 4194304);    // 4 MiB
    __hip_bfloat16* Vtg = (__hip_bfloat16*)(ws + 8388608);    // 4 MiB
    __hip_bfloat16* OTb = (__hip_bfloat16*)(ws + 12582912);   // 32 MiB
    __hip_bfloat16* Wpb = (__hip_bfloat16*)(ws + 46137344);   // 96 KiB
    __hip_bfloat16* xT  = (__hip_bfloat16*)(ws + 46235648);   // 2 MiB
    float* frames0 = (float*)(ws + 48332800);                 // 48 KiB
    float* partial = (float*)(ws + 48381952);                 // 512 KiB
    double* sums   = (double*)(ws + 48906240);                // 256 B
    float* Lp      = (float*)(ws + 48906496);                 // 1 MiB
    __hip_bfloat16* Wb  = (__hip_bfloat16*)(ws + 49955072);   // 8 KiB
    unsigned* counter   = (unsigned*)(ws + 49963264);         // 4 B

    hipLaunchKernelGGL(prep_all, dim3(260), dim3(256), 0, stream,
                       xs, gamma, beta, q_w, kv_w, proj_w, xT, Wpb, Wb, counter);
    hipLaunchKernelGGL(qkv_mfma, dim3(32, 12, 4), dim3(256), 0, stream,
                       xT, Wpb, Qg, Kg, Vtg);
    hipLaunchKernelGGL(attn_mfma, dim3(16, 8, KSPLIT), dim3(512), 0, stream,
                       Qg, Kg, Vtg, OTb, Lp);
    hipLaunchKernelGGL(proj_frames, dim3(32, 8), dim3(256), 0, stream,
                       OTb, Lp, Wb, proj_b, map_w, map_b, out, frames0);
    hipLaunchKernelGGL(chamfer_partial, dim3(NPTS / 256, NJC, 4), dim3(256), 0, stream,
                       pc1, frames0, partial);
    hipLaunchKernelGGL(chamfer_minsum, dim3(32), dim3(256), 0, stream,
                       partial, sums, counter, out + 823296);
}

// Round 14
// 75.185 us; speedup vs baseline: 1.8623x; 1.8623x over previous
//
#include <hip/hip_runtime.h>
#include <hip/hip_bf16.h>

#define NPTS 2048
#define LOG2E 1.4426950408889634f
#define NJC 16     // chamfer j-chunks
#define JCH 128    // points per chunk
#define KSPLIT 8

typedef short bf16x8 __attribute__((ext_vector_type(8)));
typedef float f32x4 __attribute__((ext_vector_type(4)));
typedef unsigned uint32x4 __attribute__((ext_vector_type(4)));
typedef __attribute__((address_space(3))) char lds_char;
typedef __attribute__((address_space(1))) const char glob_char;

union PBU { uint32x4 u; bf16x8 v; };

static __device__ __forceinline__ unsigned cvt_pk_bf16(float a, float b) {
    unsigned r;
    asm("v_cvt_pk_bf16_f32 %0, %1, %2" : "=v"(r) : "v"(a), "v"(b));
    return r;
}
static __device__ __forceinline__ float b2f(unsigned short u) {
    return __uint_as_float((unsigned)u << 16);
}

// ---------------------------------------------------------------------------
// K0 (fused): blocks 0..255 -> xT tiles; blocks 256..259 -> weight casts +
// chamfer ticket-counter zeroing.
// ---------------------------------------------------------------------------
__global__ __launch_bounds__(256) void prep_all(const float* __restrict__ xs,
                                                const float* __restrict__ gamma,
                                                const float* __restrict__ beta,
                                                const float* __restrict__ q_w,
                                                const float* __restrict__ kv_w,
                                                const float* __restrict__ proj_w,
                                                __hip_bfloat16* __restrict__ xT,
                                                __hip_bfloat16* __restrict__ Wpb,
                                                __hip_bfloat16* __restrict__ Wb,
                                                unsigned* __restrict__ counter) {
    const int bid = blockIdx.x;
    const int t = threadIdx.x;
    if (bid < 256) {
        const int fr = bid >> 5;           // b*4 + f
        const int n0 = (bid & 31) * 64;
        const float* __restrict__ A = xs + (size_t)fr * 64 * NPTS;   // [c][n]

        __shared__ float As[64][68];
        __shared__ float sg[64], sb[64];

        if (t < 64) {
            const float inv = 1.0f / sqrtf(1.0f + 1e-5f);
            sg[t] = gamma[t] * inv;
            sb[t] = beta[t];
        }
        const int tx = t & 15, ty = t >> 4;
        for (int r = 0; r < 4; ++r) {
            int row = ty + 16 * r, col = tx * 4;
            *(float4*)&As[row][col] = *(const float4*)&A[(size_t)row * NPTS + n0 + col];
        }
        __syncthreads();

        const int nl = t >> 2, c0 = (t & 3) * 16;
        bf16x8 v0, v1;
#pragma unroll
        for (int j = 0; j < 8; ++j) {
            float a = As[c0 + j][nl] * sg[c0 + j] + sb[c0 + j];
            v0[j] = (short)__bfloat16_as_ushort(__float2bfloat16(a));
        }
#pragma unroll
        for (int j = 0; j < 8; ++j) {
            float a = As[c0 + 8 + j][nl] * sg[c0 + 8 + j] + sb[c0 + 8 + j];
            v1[j] = (short)__bfloat16_as_ushort(__float2bfloat16(a));
        }
        __hip_bfloat16* dst = xT + ((size_t)fr * NPTS + n0 + nl) * 64 + c0;
        *(bf16x8*)(dst) = v0;
        *(bf16x8*)(dst + 8) = v1;
    } else {
        const int row = (bid - 256) * 256 + t;   // 0..1023
        if (row < 768) {
            const float* src;
            float scale;
            if (row < 256) { src = q_w + row * 64;          scale = 0.125f * LOG2E; }
            else           { src = kv_w + (row - 256) * 64; scale = 1.0f; }
            for (int c = 0; c < 64; ++c)
                Wpb[row * 64 + c] = __float2bfloat16(src[c] * scale);
        } else if (row < 832) {
            const int j = row - 768;
            for (int c = 0; c < 64; ++c)
                Wb[j * 64 + c] = __float2bfloat16(proj_w[j * 64 + c]);
        } else if (row == 1023) {
            *counter = 0;          // chamfer ticket counter, zeroed every call
        }
    }
}

// ---------------------------------------------------------------------------
// K1: QKV via MFMA, zero LDS (verified round-9 version).
// ---------------------------------------------------------------------------
__global__ __launch_bounds__(256) void qkv_mfma(const __hip_bfloat16* __restrict__ xT,
                                                const __hip_bfloat16* __restrict__ Wpb,
                                                __hip_bfloat16* __restrict__ Qg,
                                                __hip_bfloat16* __restrict__ Kg,
                                                __hip_bfloat16* __restrict__ Vtg) {
    const int bf = blockIdx.z;            // b*2 + f01
    const int b = bf >> 1, f01 = bf & 1;
    const int jt = blockIdx.y;            // 0..11
    const int f_src = (jt < 4) ? f01 : (3 - f01);
    const int n0 = blockIdx.x * 64;

    const int t = threadIdx.x, lane = t & 63, w = t >> 6;
    const int l15 = lane & 15, g = (lane >> 4) & 3;

    const __hip_bfloat16* __restrict__ xfb = xT + (size_t)(b * 4 + f_src) * NPTS * 64;

    if (jt < 8) {
        const __hip_bfloat16* wp = Wpb + (size_t)(jt * 64 + w * 16 + l15) * 64 + g * 8;
        bf16x8 wf0 = *(const bf16x8*)(wp);
        bf16x8 wf1 = *(const bf16x8*)(wp + 32);
        __hip_bfloat16* __restrict__ dst = (jt < 4 ? Qg : Kg) + (size_t)bf * NPTS * 256;
        const int jb = (jt & 3) * 64 + w * 16 + g * 4;
#pragma unroll
        for (int nt = 0; nt < 4; ++nt) {
            const __hip_bfloat16* xp = xfb + (size_t)(n0 + nt * 16 + l15) * 64 + g * 8;
            bf16x8 xf0 = *(const bf16x8*)(xp);
            bf16x8 xf1 = *(const bf16x8*)(xp + 32);
            f32x4 d = (f32x4){0.f, 0.f, 0.f, 0.f};
            d = __builtin_amdgcn_mfma_f32_16x16x32_bf16(wf0, xf0, d, 0, 0, 0);
            d = __builtin_amdgcn_mfma_f32_16x16x32_bf16(wf1, xf1, d, 0, 0, 0);
            uint2 pv;
            pv.x = cvt_pk_bf16(d[0], d[1]);
            pv.y = cvt_pk_bf16(d[2], d[3]);
            *(uint2*)&dst[(size_t)(n0 + nt * 16 + l15) * 256 + jb] = pv;
        }
    } else {
        const __hip_bfloat16* xp = xfb + (size_t)(n0 + w * 16 + l15) * 64 + g * 8;
        bf16x8 xf0 = *(const bf16x8*)(xp);
        bf16x8 xf1 = *(const bf16x8*)(xp + 32);
        __hip_bfloat16* __restrict__ dst = Vtg + (size_t)bf * 256 * NPTS;
#pragma unroll
        for (int tj = 0; tj < 4; ++tj) {
            const int ch = (jt - 8) * 64 + tj * 16 + l15;
            const __hip_bfloat16* wp = Wpb + (size_t)(512 + ch) * 64 + g * 8;
            bf16x8 wf0 = *(const bf16x8*)(wp);
            bf16x8 wf1 = *(const bf16x8*)(wp + 32);
            f32x4 d = (f32x4){0.f, 0.f, 0.f, 0.f};
            d = __builtin_amdgcn_mfma_f32_16x16x32_bf16(xf0, wf0, d, 0, 0, 0);
            d = __builtin_amdgcn_mfma_f32_16x16x32_bf16(xf1, wf1, d, 0, 0, 0);
            uint2 pv;
            pv.x = cvt_pk_bf16(d[0], d[1]);
            pv.y = cvt_pk_bf16(d[2], d[3]);
            *(uint2*)&dst[(size_t)ch * NPTS + n0 + w * 16 + g * 4] = pv;
        }
    }
}

// ---------------------------------------------------------------------------
// K2: MFMA flash attention — R12-verified 256-thread kernel (4 waves, 32 q
// per wave, quad-buffered LDS, one barrier/tile), with prefetch depth 3:
// stage issued AFTER the barrier (write target buf (t+3)&3 == (t-1)&3 is
// only safe post-barrier, when all waves have finished tile(t-1)).
// Steady-state wait stays vmcnt(4) (3 stages x 2 loads outstanding).
// ---------------------------------------------------------------------------
__global__ __launch_bounds__(256, 4) void attn_mfma(const __hip_bfloat16* __restrict__ Qg,
                                                    const __hip_bfloat16* __restrict__ Kg,
                                                    const __hip_bfloat16* __restrict__ Vtg,
                                                    __hip_bfloat16* __restrict__ OTb,
                                                    float* __restrict__ Lp) {
    const int combo = blockIdx.x;          // bf*4 + h
    const int bf = combo >> 2, h = combo & 3;
    const int n0 = blockIdx.y * 128;
    const int split = blockIdx.z;
    const int kbase = split * (NPTS / KSPLIT);
    const int NT = NPTS / KSPLIT / 32;     // 8 k-tiles of 32 per split

    __shared__ __align__(16) char smem[32768];   // 4 bufs x (K 4KB | V 4KB)

    const int t = threadIdx.x;
    const int lane = t & 63, w = t >> 6;
    const int l15 = lane & 15, g = (lane >> 4) & 3;

    const int krow = w * 8 + (lane >> 3), kslot = lane & 7;
    const int vrow = w * 16 + (lane >> 2), vslot = lane & 3;
    const int kcs = (kslot ^ (krow & 7)) * 8;
    const int vcs = (vslot ^ ((vrow >> 1) & 3)) * 8;

    const __hip_bfloat16* qbase =
        Qg + ((size_t)bf * NPTS + n0 + w * 32 + l15) * 256 + h * 64 + g * 8;
    bf16x8 qf[2][2];
    qf[0][0] = *(const bf16x8*)(qbase);
    qf[0][1] = *(const bf16x8*)(qbase + 32);
    qf[1][0] = *(const bf16x8*)(qbase + 16 * 256);
    qf[1][1] = *(const bf16x8*)(qbase + 16 * 256 + 32);

    const __hip_bfloat16* kgb = Kg + (size_t)bf * NPTS * 256 + h * 64;
    const __hip_bfloat16* vgb = Vtg + ((size_t)bf * 256 + h * 64) * NPTS;

    int koff[2][2], voff[4];
#pragma unroll
    for (int tt = 0; tt < 2; ++tt) {
        const int row = tt * 16 + l15;
#pragma unroll
        for (int s = 0; s < 2; ++s)
            koff[tt][s] = row * 128 + (((s * 4 + g) ^ (row & 7)) << 4);
    }
#pragma unroll
    for (int ct = 0; ct < 4; ++ct) {
        const int row = ct * 16 + l15;
        voff[ct] = 4096 + row * 64 + ((g ^ ((row >> 1) & 3)) << 4);
    }

    f32x4 oacc[2][4];
    float lsum[2] = {0.f, 0.f};
#pragma unroll
    for (int f = 0; f < 2; ++f)
#pragma unroll
        for (int r = 0; r < 4; ++r) oacc[f][r] = (f32x4){0.f, 0.f, 0.f, 0.f};

    auto stage = [&](int kt) {
        const int bsel = kt & 3;
        const __hip_bfloat16* ksrc = kgb + (size_t)(kbase + kt * 32 + krow) * 256 + kcs;
        __builtin_amdgcn_global_load_lds((const glob_char*)ksrc,
            (lds_char*)(smem + bsel * 8192 + w * 1024), 16, 0, 0);
        const __hip_bfloat16* vsrc = vgb + (size_t)vrow * NPTS + kbase + kt * 32 + vcs;
        __builtin_amdgcn_global_load_lds((const glob_char*)vsrc,
            (lds_char*)(smem + bsel * 8192 + 4096 + w * 1024), 16, 0, 0);
    };

    auto tile = [&](int kt) {
        const char* B = smem + (kt & 3) * 8192;
        bf16x8 kf[2][2];
#pragma unroll
        for (int tt = 0; tt < 2; ++tt)
#pragma unroll
            for (int s = 0; s < 2; ++s)
                kf[tt][s] = *(const bf16x8*)(B + koff[tt][s]);

        bf16x8 pb[2];
#pragma unroll
        for (int f = 0; f < 2; ++f) {
            f32x4 st0 = (f32x4){0.f, 0.f, 0.f, 0.f}, st1 = st0;
            st0 = __builtin_amdgcn_mfma_f32_16x16x32_bf16(kf[0][0], qf[f][0], st0, 0, 0, 0);
            st0 = __builtin_amdgcn_mfma_f32_16x16x32_bf16(kf[0][1], qf[f][1], st0, 0, 0, 0);
            st1 = __builtin_amdgcn_mfma_f32_16x16x32_bf16(kf[1][0], qf[f][0], st1, 0, 0, 0);
            st1 = __builtin_amdgcn_mfma_f32_16x16x32_bf16(kf[1][1], qf[f][1], st1, 0, 0, 0);
            float p00 = exp2f(st0[0]);
            float p01 = exp2f(st0[1]);
            float p02 = exp2f(st0[2]);
            float p03 = exp2f(st0[3]);
            float p10 = exp2f(st1[0]);
            float p11 = exp2f(st1[1]);
            float p12 = exp2f(st1[2]);
            float p13 = exp2f(st1[3]);
            lsum[f] += ((p00 + p01) + (p02 + p03)) + ((p10 + p11) + (p12 + p13));
            unsigned x0 = cvt_pk_bf16(p00, p01);
            unsigned x1 = cvt_pk_bf16(p02, p03);
            unsigned y0 = cvt_pk_bf16(p10, p11);
            unsigned y1 = cvt_pk_bf16(p12, p13);
            asm("v_permlane32_swap_b32 %0, %1" : "+v"(x0), "+v"(y0));
            asm("v_permlane16_swap_b32 %0, %1" : "+v"(x0), "+v"(y0));
            asm("v_permlane32_swap_b32 %0, %1" : "+v"(x1), "+v"(y1));
            asm("v_permlane16_swap_b32 %0, %1" : "+v"(x1), "+v"(y1));
            PBU pu;
            pu.u = (uint32x4){x0, x1, y0, y1};
            pb[f] = pu.v;
        }

#pragma unroll
        for (int ct = 0; ct < 4; ++ct) {
            bf16x8 vf = *(const bf16x8*)(B + voff[ct]);
            oacc[0][ct] = __builtin_amdgcn_mfma_f32_16x16x32_bf16(vf, pb[0], oacc[0][ct], 0, 0, 0);
            oacc[1][ct] = __builtin_amdgcn_mfma_f32_16x16x32_bf16(vf, pb[1], oacc[1][ct], 0, 0, 0);
        }
    };

    stage(0);
    stage(1);
    stage(2);
    for (int kt = 0; kt < NT - 3; ++kt) {
        asm volatile("s_waitcnt vmcnt(4)" ::: "memory");
        __builtin_amdgcn_s_barrier();
        asm volatile("" ::: "memory");
        stage(kt + 3);                 // buf (kt+3)&3 == (kt-1)&3: safe post-barrier
        tile(kt);
    }
    asm volatile("s_waitcnt vmcnt(4)" ::: "memory");
    __builtin_amdgcn_s_barrier();
    asm volatile("" ::: "memory");
    tile(NT - 3);
    asm volatile("s_waitcnt vmcnt(2)" ::: "memory");
    __builtin_amdgcn_s_barrier();
    asm volatile("" ::: "memory");
    tile(NT - 2);
    asm volatile("s_waitcnt vmcnt(0)" ::: "memory");
    __builtin_amdgcn_s_barrier();
    asm volatile("" ::: "memory");
    tile(NT - 1);

    float l0 = lsum[0], l1 = lsum[1];
    l0 += __shfl_xor(l0, 16);
    l0 += __shfl_xor(l0, 32);
    l1 += __shfl_xor(l1, 16);
    l1 += __shfl_xor(l1, 32);
    const int qq = n0 + w * 32 + l15;
    if (lane < 16) {
        Lp[(size_t)(split * 16 + combo) * NPTS + qq] = l0;
        Lp[(size_t)(split * 16 + combo) * NPTS + qq + 16] = l1;
    }

    __hip_bfloat16* __restrict__ Op = OTb + (size_t)(split * 16 + combo) * 64 * NPTS;
#pragma unroll
    for (int ct = 0; ct < 4; ++ct)
#pragma unroll
        for (int r = 0; r < 4; ++r) {
            Op[(size_t)(ct * 16 + g * 4 + r) * NPTS + qq] = __float2bfloat16(oacc[0][ct][r]);
            Op[(size_t)(ct * 16 + g * 4 + r) * NPTS + qq + 16] = __float2bfloat16(oacc[1][ct][r]);
        }
}

// ---------------------------------------------------------------------------
// K3: combine KSPLIT partials + normalize -> Xn bf16 (transposed), MFMA proj,
// bias, xaS f32; frames from xaS.  (verified round-11 version)
// ---------------------------------------------------------------------------
__global__ __launch_bounds__(256) void proj_frames(const __hip_bfloat16* __restrict__ OTb,
                                                   const float* __restrict__ Lp,
                                                   const __hip_bfloat16* __restrict__ Wb,
                                                   const float* __restrict__ proj_b,
                                                   const float* __restrict__ map_w,
                                                   const float* __restrict__ map_b,
                                                   float* __restrict__ out,
                                                   float* __restrict__ frames0) {
    const int bh = blockIdx.y, b = bh >> 2, h = bh & 3;
    const int n0 = blockIdx.x * 64;
    const int cf0 = (b * 2 + 0) * 4 + h;
    const int cf1 = (b * 2 + 1) * 4 + h;

    __shared__ __align__(16) unsigned short Xn[64][72];  // [n][c] bf16
    __shared__ float xaS[64][68];                        // [n][j]

    const int t = threadIdx.x;
    const int lane = t & 63, w = t >> 6;
    const int tx = t & 15, ty = t >> 4;
    const int l15 = lane & 15, g = (lane >> 4) & 3;
    const int nc = n0 + tx * 4;

    float4 L0 = make_float4(0.f, 0.f, 0.f, 0.f), L1 = L0;
#pragma unroll
    for (int s = 0; s < KSPLIT; ++s) {
        float4 a = *(const float4*)&Lp[(size_t)(s * 16 + cf0) * NPTS + nc];
        L0.x += a.x; L0.y += a.y; L0.z += a.z; L0.w += a.w;
        float4 c = *(const float4*)&Lp[(size_t)(s * 16 + cf1) * NPTS + nc];
        L1.x += c.x; L1.y += c.y; L1.z += c.z; L1.w += c.w;
    }
    float4 inv0 = make_float4(1.f / L0.x, 1.f / L0.y, 1.f / L0.z, 1.f / L0.w);
    float4 inv1 = make_float4(1.f / L1.x, 1.f / L1.y, 1.f / L1.z, 1.f / L1.w);

    for (int r = 0; r < 4; ++r) {
        int row = ty + 16 * r, col = tx * 4;   // row = c, col = n_local
        float x0 = 0.f, x1 = 0.f, x2 = 0.f, x3 = 0.f;
        float y0 = 0.f, y1 = 0.f, y2 = 0.f, y3 = 0.f;
#pragma unroll
        for (int s = 0; s < KSPLIT; ++s) {
            ushort4 u0 = *(const ushort4*)&OTb[((size_t)(s * 16 + cf0) * 64 + row) * NPTS + n0 + col];
            ushort4 u1 = *(const ushort4*)&OTb[((size_t)(s * 16 + cf1) * 64 + row) * NPTS + n0 + col];
            x0 += b2f(u0.x); x1 += b2f(u0.y); x2 += b2f(u0.z); x3 += b2f(u0.w);
            y0 += b2f(u1.x); y1 += b2f(u1.y); y2 += b2f(u1.z); y3 += b2f(u1.w);
        }
        Xn[col + 0][row] = __bfloat16_as_ushort(__float2bfloat16(x0 * inv0.x + y0 * inv1.x));
        Xn[col + 1][row] = __bfloat16_as_ushort(__float2bfloat16(x1 * inv0.y + y1 * inv1.y));
        Xn[col + 2][row] = __bfloat16_as_ushort(__float2bfloat16(x2 * inv0.z + y2 * inv1.z));
        Xn[col + 3][row] = __bfloat16_as_ushort(__float2bfloat16(x3 * inv0.w + y3 * inv1.w));
    }
    __syncthreads();

    {
        const __hip_bfloat16* wp = Wb + (size_t)(w * 16 + l15) * 64 + g * 8;
        bf16x8 wf0 = *(const bf16x8*)(wp);
        bf16x8 wf1 = *(const bf16x8*)(wp + 32);
        float pbias[4];
#pragma unroll
        for (int r = 0; r < 4; ++r) pbias[r] = proj_b[w * 16 + g * 4 + r];
#pragma unroll
        for (int nt = 0; nt < 4; ++nt) {
            bf16x8 xf0 = *(const bf16x8*)&Xn[nt * 16 + l15][g * 8];
            bf16x8 xf1 = *(const bf16x8*)&Xn[nt * 16 + l15][g * 8 + 32];
            f32x4 d = (f32x4){0.f, 0.f, 0.f, 0.f};
            d = __builtin_amdgcn_mfma_f32_16x16x32_bf16(wf0, xf0, d, 0, 0, 0);
            d = __builtin_amdgcn_mfma_f32_16x16x32_bf16(wf1, xf1, d, 0, 0, 0);
            float4 v = make_float4(d[0] + pbias[0], d[1] + pbias[1],
                                   d[2] + pbias[2], d[3] + pbias[3]);
            *(float4*)&xaS[nt * 16 + l15][w * 16 + g * 4] = v;
        }
    }
    __syncthreads();

    if (h >= 1) {
        float* __restrict__ xa_out = out + (size_t)(b * 3 + h - 1) * NPTS * 64;
        for (int r = 0; r < 4; ++r) {
            int n = ty + 16 * r;
            float4 v = *(const float4*)&xaS[n][tx * 4];
            *(float4*)&xa_out[(size_t)(n0 + n) * 64 + tx * 4] = v;
        }
    }

    if (t < 192) {
        int r = t / 3, j = t % 3;
        float s = map_b[j];
        for (int c = 0; c < 64; ++c) s += xaS[r][c] * map_w[j * 64 + c];
        int n = n0 + r;
        if (h == 0) frames0[((size_t)b * NPTS + n) * 3 + j] = s;
        else        out[786432 + ((size_t)(b * 3 + h - 1) * NPTS + n) * 3 + j] = s;
    }
}

// ---------------------------------------------------------------------------
// K4a: chamfer partial mins.  grid (NPTS/256, NJC, 4); z = dir*2 + b.
// ---------------------------------------------------------------------------
__global__ __launch_bounds__(256) void chamfer_partial(const float* __restrict__ pc1,
                                                       const float* __restrict__ frames0,
                                                       float* __restrict__ partial) {
    const int z = blockIdx.z;          // dir*2 + b
    const int dir = z >> 1, b = z & 1;
    const int i = blockIdx.x * 256 + threadIdx.x;
    const int j0 = blockIdx.y * JCH;
    const float* __restrict__ px = pc1 + (size_t)b * 3 * NPTS;
    const float* __restrict__ fr = frames0 + (size_t)b * NPTS * 3;

    __shared__ float4 sj[JCH];
    if (threadIdx.x < JCH) {
        int jj = j0 + threadIdx.x;
        float bx = px[jj], by = px[NPTS + jj], bz = px[2 * NPTS + jj];
        if (dir == 1) { bx += fr[jj * 3]; by += fr[jj * 3 + 1]; bz += fr[jj * 3 + 2]; }
        sj[threadIdx.x] = make_float4(bx, by, bz, bx * bx + by * by + bz * bz);
    }
    float ax = px[i], ay = px[NPTS + i], az = px[2 * NPTS + i];
    if (dir == 0) { ax += fr[i * 3]; ay += fr[i * 3 + 1]; az += fr[i * 3 + 2]; }
    const float a2 = ax * ax + ay * ay + az * az;
    __syncthreads();

    float best = 1e30f;
#pragma unroll 4
    for (int k = 0; k < JCH; ++k) {
        float4 p = sj[k];
        float d = a2 + p.w - 2.0f * (ax * p.x + ay * p.y + az * p.z);
        best = fminf(best, d);
    }
    partial[((size_t)z * NJC + blockIdx.y) * NPTS + i] = best;
}

// ---------------------------------------------------------------------------
// K4b (fused): min over chunks + per-block sum; LAST block (device-scope
// ticket) sums the 32 block sums in fixed order -> loss.
// ---------------------------------------------------------------------------
__global__ __launch_bounds__(256) void chamfer_minsum(const float* __restrict__ partial,
                                                      double* __restrict__ sums,
                                                      unsigned* __restrict__ counter,
                                                      float* __restrict__ loss_out) {
    const int gid = blockIdx.x * 256 + threadIdx.x;
    const int z = gid >> 11, i = gid & 2047;
    float best = 1e30f;
#pragma unroll
    for (int c = 0; c < NJC; ++c)
        best = fminf(best, partial[((size_t)z * NJC + c) * NPTS + i]);
    __shared__ double sm[256];
    sm[threadIdx.x] = (double)best;
    __syncthreads();
    for (int off = 128; off > 0; off >>= 1) {
        if (threadIdx.x < off) sm[threadIdx.x] += sm[threadIdx.x + off];
        __syncthreads();
    }
    if (threadIdx.x == 0) {
        sums[blockIdx.x] = sm[0];
        __threadfence();                            // release sums device-wide
        unsigned prev = atomicAdd(counter, 1u);     // device-scope arrival
        if (prev == 31u) {
            __threadfence();                        // acquire others' sums
            double s = 0.0;
            for (int k = 0; k < 32; ++k) s += sums[k];
            loss_out[0] = (float)(s / 4096.0);
            *counter = 0;
        }
    }
}

// ---------------------------------------------------------------------------
extern "C" void kernel_launch(void* const* d_in, const int* in_sizes, int n_in,
                              void* d_out, int out_size, void* d_ws, size_t ws_size,
                              hipStream_t stream) {
    const float* xs     = (const float*)d_in[0];
    const float* pc1    = (const float*)d_in[1];
    // d_in[2] = pc2 (unused by reference)
    const float* gamma  = (const float*)d_in[3];
    const float* beta   = (const float*)d_in[4];
    const float* q_w    = (const float*)d_in[5];
    const float* kv_w   = (const float*)d_in[6];
    const float* proj_w = (const float*)d_in[7];
    const float* proj_b = (const float*)d_in[8];
    const float* map_w  = (const float*)d_in[9];
    const float* map_b  = (const float*)d_in[10];
    float* out = (float*)d_out;

    char* ws = (char*)d_ws;
    __hip_bfloat16* Qg  = (__hip_bfloat16*)(ws);              // 4 MiB
    __hip_bfloat16* Kg  = (__hip_bfloat16*)(ws + 4194304);    // 4 MiB
    __hip_bfloat16* Vtg = (__hip_bfloat16*)(ws + 8388608);    // 4 MiB
    __hip_bfloat16* OTb = (__hip_bfloat16*)(ws + 12582912);   // 32 MiB
    __hip_bfloat16* Wpb = (__hip_bfloat16*)(ws + 46137344);   // 96 KiB
    __hip_bfloat16* xT  = (__hip_bfloat16*)(ws + 46235648);   // 2 MiB
    float* frames0 = (float*)(ws + 48332800);                 // 48 KiB
    float* partial = (float*)(ws + 48381952);                 // 512 KiB
    double* sums   = (double*)(ws + 48906240);                // 256 B
    float* Lp      = (float*)(ws + 48906496);                 // 1 MiB
    __hip_bfloat16* Wb  = (__hip_bfloat16*)(ws + 49955072);   // 8 KiB
    unsigned* counter   = (unsigned*)(ws + 49963264);         // 4 B

    hipLaunchKernelGGL(prep_all, dim3(260), dim3(256), 0, stream,
                       xs, gamma, beta, q_w, kv_w, proj_w, xT, Wpb, Wb, counter);
    hipLaunchKernelGGL(qkv_mfma, dim3(32, 12, 4), dim3(256), 0, stream,
                       xT, Wpb, Qg, Kg, Vtg);
    hipLaunchKernelGGL(attn_mfma, dim3(16, 16, KSPLIT), dim3(256), 0, stream,
                       Qg, Kg, Vtg, OTb, Lp);
    hipLaunchKernelGGL(proj_frames, dim3(32, 8), dim3(256), 0, stream,
                       OTb, Lp, Wb, proj_b, map_w, map_b, out, frames0);
    hipLaunchKernelGGL(chamfer_partial, dim3(NPTS / 256, NJC, 4), dim3(256), 0, stream,
                       pc1, frames0, partial);
    hipLaunchKernelGGL(chamfer_minsum, dim3(32), dim3(256), 0, stream,
                       partial, sums, counter, out + 823296);
}

// Round 15
// 74.726 us; speedup vs baseline: 1.8738x; 1.0061x over previous
//
#include <hip/hip_runtime.h>
#include <hip/hip_bf16.h>

#define NPTS 2048
#define LOG2E 1.4426950408889634f
#define NJC 16     // chamfer j-chunks
#define JCH 128    // points per chunk
#define KSPLIT 8

typedef short bf16x8 __attribute__((ext_vector_type(8)));
typedef float f32x4 __attribute__((ext_vector_type(4)));
typedef unsigned uint32x4 __attribute__((ext_vector_type(4)));
typedef __attribute__((address_space(3))) char lds_char;
typedef __attribute__((address_space(1))) const char glob_char;

union PBU { uint32x4 u; bf16x8 v; };

static __device__ __forceinline__ unsigned cvt_pk_bf16(float a, float b) {
    unsigned r;
    asm("v_cvt_pk_bf16_f32 %0, %1, %2" : "=v"(r) : "v"(a), "v"(b));
    return r;
}
static __device__ __forceinline__ float b2f(unsigned short u) {
    return __uint_as_float((unsigned)u << 16);
}
// monotonic mapping: unsigned order == float order
static __device__ __forceinline__ unsigned f2mono(float f) {
    unsigned u = __float_as_uint(f);
    return ((int)u < 0) ? ~u : (u | 0x80000000u);
}
static __device__ __forceinline__ float mono2f(unsigned m) {
    unsigned u = (m & 0x80000000u) ? (m & 0x7FFFFFFFu) : ~m;
    return __uint_as_float(u);
}

// ---------------------------------------------------------------------------
// K0 (fused): blocks 0..255 -> xT tiles; blocks 256..259 -> weight casts +
// chamfer minsU init (0xFFFFFFFF) + ticket-counter zeroing.
// ---------------------------------------------------------------------------
__global__ __launch_bounds__(256) void prep_all(const float* __restrict__ xs,
                                                const float* __restrict__ gamma,
                                                const float* __restrict__ beta,
                                                const float* __restrict__ q_w,
                                                const float* __restrict__ kv_w,
                                                const float* __restrict__ proj_w,
                                                __hip_bfloat16* __restrict__ xT,
                                                __hip_bfloat16* __restrict__ Wpb,
                                                __hip_bfloat16* __restrict__ Wb,
                                                unsigned* __restrict__ minsU,
                                                unsigned* __restrict__ counter) {
    const int bid = blockIdx.x;
    const int t = threadIdx.x;
    if (bid < 256) {
        const int fr = bid >> 5;           // b*4 + f
        const int n0 = (bid & 31) * 64;
        const float* __restrict__ A = xs + (size_t)fr * 64 * NPTS;   // [c][n]

        __shared__ float As[64][68];
        __shared__ float sg[64], sb[64];

        if (t < 64) {
            const float inv = 1.0f / sqrtf(1.0f + 1e-5f);
            sg[t] = gamma[t] * inv;
            sb[t] = beta[t];
        }
        const int tx = t & 15, ty = t >> 4;
        for (int r = 0; r < 4; ++r) {
            int row = ty + 16 * r, col = tx * 4;
            *(float4*)&As[row][col] = *(const float4*)&A[(size_t)row * NPTS + n0 + col];
        }
        __syncthreads();

        const int nl = t >> 2, c0 = (t & 3) * 16;
        bf16x8 v0, v1;
#pragma unroll
        for (int j = 0; j < 8; ++j) {
            float a = As[c0 + j][nl] * sg[c0 + j] + sb[c0 + j];
            v0[j] = (short)__bfloat16_as_ushort(__float2bfloat16(a));
        }
#pragma unroll
        for (int j = 0; j < 8; ++j) {
            float a = As[c0 + 8 + j][nl] * sg[c0 + 8 + j] + sb[c0 + 8 + j];
            v1[j] = (short)__bfloat16_as_ushort(__float2bfloat16(a));
        }
        __hip_bfloat16* dst = xT + ((size_t)fr * NPTS + n0 + nl) * 64 + c0;
        *(bf16x8*)(dst) = v0;
        *(bf16x8*)(dst + 8) = v1;
    } else {
        const int row = (bid - 256) * 256 + t;   // 0..1023
        if (row < 768) {
            const float* src;
            float scale;
            if (row < 256) { src = q_w + row * 64;          scale = 0.125f * LOG2E; }
            else           { src = kv_w + (row - 256) * 64; scale = 1.0f; }
            for (int c = 0; c < 64; ++c)
                Wpb[row * 64 + c] = __float2bfloat16(src[c] * scale);
        } else if (row < 832) {
            const int j = row - 768;
            for (int c = 0; c < 64; ++c)
                Wb[j * 64 + c] = __float2bfloat16(proj_w[j * 64 + c]);
        } else if (row == 1023) {
            *counter = 0;          // chamfer ticket counter, zeroed every call
        }
        // init chamfer minsU: 4 blocks x 256 thr x 8 = 8192 entries
        unsigned* mp = minsU + (size_t)(bid - 256) * 2048 + t * 8;
#pragma unroll
        for (int k = 0; k < 8; ++k) mp[k] = 0xFFFFFFFFu;
    }
}

// ---------------------------------------------------------------------------
// K1: QKV via MFMA, zero LDS (verified round-9 version).
// ---------------------------------------------------------------------------
__global__ __launch_bounds__(256) void qkv_mfma(const __hip_bfloat16* __restrict__ xT,
                                                const __hip_bfloat16* __restrict__ Wpb,
                                                __hip_bfloat16* __restrict__ Qg,
                                                __hip_bfloat16* __restrict__ Kg,
                                                __hip_bfloat16* __restrict__ Vtg) {
    const int bf = blockIdx.z;            // b*2 + f01
    const int b = bf >> 1, f01 = bf & 1;
    const int jt = blockIdx.y;            // 0..11
    const int f_src = (jt < 4) ? f01 : (3 - f01);
    const int n0 = blockIdx.x * 64;

    const int t = threadIdx.x, lane = t & 63, w = t >> 6;
    const int l15 = lane & 15, g = (lane >> 4) & 3;

    const __hip_bfloat16* __restrict__ xfb = xT + (size_t)(b * 4 + f_src) * NPTS * 64;

    if (jt < 8) {
        const __hip_bfloat16* wp = Wpb + (size_t)(jt * 64 + w * 16 + l15) * 64 + g * 8;
        bf16x8 wf0 = *(const bf16x8*)(wp);
        bf16x8 wf1 = *(const bf16x8*)(wp + 32);
        __hip_bfloat16* __restrict__ dst = (jt < 4 ? Qg : Kg) + (size_t)bf * NPTS * 256;
        const int jb = (jt & 3) * 64 + w * 16 + g * 4;
#pragma unroll
        for (int nt = 0; nt < 4; ++nt) {
            const __hip_bfloat16* xp = xfb + (size_t)(n0 + nt * 16 + l15) * 64 + g * 8;
            bf16x8 xf0 = *(const bf16x8*)(xp);
            bf16x8 xf1 = *(const bf16x8*)(xp + 32);
            f32x4 d = (f32x4){0.f, 0.f, 0.f, 0.f};
            d = __builtin_amdgcn_mfma_f32_16x16x32_bf16(wf0, xf0, d, 0, 0, 0);
            d = __builtin_amdgcn_mfma_f32_16x16x32_bf16(wf1, xf1, d, 0, 0, 0);
            uint2 pv;
            pv.x = cvt_pk_bf16(d[0], d[1]);
            pv.y = cvt_pk_bf16(d[2], d[3]);
            *(uint2*)&dst[(size_t)(n0 + nt * 16 + l15) * 256 + jb] = pv;
        }
    } else {
        const __hip_bfloat16* xp = xfb + (size_t)(n0 + w * 16 + l15) * 64 + g * 8;
        bf16x8 xf0 = *(const bf16x8*)(xp);
        bf16x8 xf1 = *(const bf16x8*)(xp + 32);
        __hip_bfloat16* __restrict__ dst = Vtg + (size_t)bf * 256 * NPTS;
#pragma unroll
        for (int tj = 0; tj < 4; ++tj) {
            const int ch = (jt - 8) * 64 + tj * 16 + l15;
            const __hip_bfloat16* wp = Wpb + (size_t)(512 + ch) * 64 + g * 8;
            bf16x8 wf0 = *(const bf16x8*)(wp);
            bf16x8 wf1 = *(const bf16x8*)(wp + 32);
            f32x4 d = (f32x4){0.f, 0.f, 0.f, 0.f};
            d = __builtin_amdgcn_mfma_f32_16x16x32_bf16(xf0, wf0, d, 0, 0, 0);
            d = __builtin_amdgcn_mfma_f32_16x16x32_bf16(xf1, wf1, d, 0, 0, 0);
            uint2 pv;
            pv.x = cvt_pk_bf16(d[0], d[1]);
            pv.y = cvt_pk_bf16(d[2], d[3]);
            *(uint2*)&dst[(size_t)ch * NPTS + n0 + w * 16 + g * 4] = pv;
        }
    }
}

// ---------------------------------------------------------------------------
// K2: MFMA flash attention — EXACT R12-verified schedule (75.01 us total):
// 4 waves x 32 q, quad-buffered LDS, stage(kt+2) -> vmcnt(4) -> barrier ->
// tile(kt); tail vmcnt(2)/(0).  FROZEN — do not touch.
// ---------------------------------------------------------------------------
__global__ __launch_bounds__(256, 4) void attn_mfma(const __hip_bfloat16* __restrict__ Qg,
                                                    const __hip_bfloat16* __restrict__ Kg,
                                                    const __hip_bfloat16* __restrict__ Vtg,
                                                    __hip_bfloat16* __restrict__ OTb,
                                                    float* __restrict__ Lp) {
    const int combo = blockIdx.x;          // bf*4 + h
    const int bf = combo >> 2, h = combo & 3;
    const int n0 = blockIdx.y * 128;
    const int split = blockIdx.z;
    const int kbase = split * (NPTS / KSPLIT);
    const int NT = NPTS / KSPLIT / 32;     // 8 k-tiles of 32 per split

    __shared__ __align__(16) char smem[32768];   // 4 bufs x (K 4KB | V 4KB)

    const int t = threadIdx.x;
    const int lane = t & 63, w = t >> 6;
    const int l15 = lane & 15, g = (lane >> 4) & 3;

    const int krow = w * 8 + (lane >> 3), kslot = lane & 7;
    const int vrow = w * 16 + (lane >> 2), vslot = lane & 3;
    const int kcs = (kslot ^ (krow & 7)) * 8;
    const int vcs = (vslot ^ ((vrow >> 1) & 3)) * 8;

    const __hip_bfloat16* qbase =
        Qg + ((size_t)bf * NPTS + n0 + w * 32 + l15) * 256 + h * 64 + g * 8;
    bf16x8 qf[2][2];
    qf[0][0] = *(const bf16x8*)(qbase);
    qf[0][1] = *(const bf16x8*)(qbase + 32);
    qf[1][0] = *(const bf16x8*)(qbase + 16 * 256);
    qf[1][1] = *(const bf16x8*)(qbase + 16 * 256 + 32);

    const __hip_bfloat16* kgb = Kg + (size_t)bf * NPTS * 256 + h * 64;
    const __hip_bfloat16* vgb = Vtg + ((size_t)bf * 256 + h * 64) * NPTS;

    int koff[2][2], voff[4];
#pragma unroll
    for (int tt = 0; tt < 2; ++tt) {
        const int row = tt * 16 + l15;
#pragma unroll
        for (int s = 0; s < 2; ++s)
            koff[tt][s] = row * 128 + (((s * 4 + g) ^ (row & 7)) << 4);
    }
#pragma unroll
    for (int ct = 0; ct < 4; ++ct) {
        const int row = ct * 16 + l15;
        voff[ct] = 4096 + row * 64 + ((g ^ ((row >> 1) & 3)) << 4);
    }

    f32x4 oacc[2][4];
    float lsum[2] = {0.f, 0.f};
#pragma unroll
    for (int f = 0; f < 2; ++f)
#pragma unroll
        for (int r = 0; r < 4; ++r) oacc[f][r] = (f32x4){0.f, 0.f, 0.f, 0.f};

    auto stage = [&](int kt) {
        const int bsel = kt & 3;
        const __hip_bfloat16* ksrc = kgb + (size_t)(kbase + kt * 32 + krow) * 256 + kcs;
        __builtin_amdgcn_global_load_lds((const glob_char*)ksrc,
            (lds_char*)(smem + bsel * 8192 + w * 1024), 16, 0, 0);
        const __hip_bfloat16* vsrc = vgb + (size_t)vrow * NPTS + kbase + kt * 32 + vcs;
        __builtin_amdgcn_global_load_lds((const glob_char*)vsrc,
            (lds_char*)(smem + bsel * 8192 + 4096 + w * 1024), 16, 0, 0);
    };

    auto tile = [&](int kt) {
        const char* B = smem + (kt & 3) * 8192;
        bf16x8 kf[2][2];
#pragma unroll
        for (int tt = 0; tt < 2; ++tt)
#pragma unroll
            for (int s = 0; s < 2; ++s)
                kf[tt][s] = *(const bf16x8*)(B + koff[tt][s]);

        bf16x8 pb[2];
#pragma unroll
        for (int f = 0; f < 2; ++f) {
            f32x4 st0 = (f32x4){0.f, 0.f, 0.f, 0.f}, st1 = st0;
            st0 = __builtin_amdgcn_mfma_f32_16x16x32_bf16(kf[0][0], qf[f][0], st0, 0, 0, 0);
            st0 = __builtin_amdgcn_mfma_f32_16x16x32_bf16(kf[0][1], qf[f][1], st0, 0, 0, 0);
            st1 = __builtin_amdgcn_mfma_f32_16x16x32_bf16(kf[1][0], qf[f][0], st1, 0, 0, 0);
            st1 = __builtin_amdgcn_mfma_f32_16x16x32_bf16(kf[1][1], qf[f][1], st1, 0, 0, 0);
            float p00 = exp2f(st0[0]);
            float p01 = exp2f(st0[1]);
            float p02 = exp2f(st0[2]);
            float p03 = exp2f(st0[3]);
            float p10 = exp2f(st1[0]);
            float p11 = exp2f(st1[1]);
            float p12 = exp2f(st1[2]);
            float p13 = exp2f(st1[3]);
            lsum[f] += ((p00 + p01) + (p02 + p03)) + ((p10 + p11) + (p12 + p13));
            unsigned x0 = cvt_pk_bf16(p00, p01);
            unsigned x1 = cvt_pk_bf16(p02, p03);
            unsigned y0 = cvt_pk_bf16(p10, p11);
            unsigned y1 = cvt_pk_bf16(p12, p13);
            asm("v_permlane32_swap_b32 %0, %1" : "+v"(x0), "+v"(y0));
            asm("v_permlane16_swap_b32 %0, %1" : "+v"(x0), "+v"(y0));
            asm("v_permlane32_swap_b32 %0, %1" : "+v"(x1), "+v"(y1));
            asm("v_permlane16_swap_b32 %0, %1" : "+v"(x1), "+v"(y1));
            PBU pu;
            pu.u = (uint32x4){x0, x1, y0, y1};
            pb[f] = pu.v;
        }

#pragma unroll
        for (int ct = 0; ct < 4; ++ct) {
            bf16x8 vf = *(const bf16x8*)(B + voff[ct]);
            oacc[0][ct] = __builtin_amdgcn_mfma_f32_16x16x32_bf16(vf, pb[0], oacc[0][ct], 0, 0, 0);
            oacc[1][ct] = __builtin_amdgcn_mfma_f32_16x16x32_bf16(vf, pb[1], oacc[1][ct], 0, 0, 0);
        }
    };

    stage(0);
    stage(1);
    for (int kt = 0; kt < NT - 2; ++kt) {
        stage(kt + 2);
        asm volatile("s_waitcnt vmcnt(4)" ::: "memory");
        __builtin_amdgcn_s_barrier();
        asm volatile("" ::: "memory");
        tile(kt);
    }
    asm volatile("s_waitcnt vmcnt(2)" ::: "memory");
    __builtin_amdgcn_s_barrier();
    asm volatile("" ::: "memory");
    tile(NT - 2);
    asm volatile("s_waitcnt vmcnt(0)" ::: "memory");
    __builtin_amdgcn_s_barrier();
    asm volatile("" ::: "memory");
    tile(NT - 1);

    float l0 = lsum[0], l1 = lsum[1];
    l0 += __shfl_xor(l0, 16);
    l0 += __shfl_xor(l0, 32);
    l1 += __shfl_xor(l1, 16);
    l1 += __shfl_xor(l1, 32);
    const int qq = n0 + w * 32 + l15;
    if (lane < 16) {
        Lp[(size_t)(split * 16 + combo) * NPTS + qq] = l0;
        Lp[(size_t)(split * 16 + combo) * NPTS + qq + 16] = l1;
    }

    __hip_bfloat16* __restrict__ Op = OTb + (size_t)(split * 16 + combo) * 64 * NPTS;
#pragma unroll
    for (int ct = 0; ct < 4; ++ct)
#pragma unroll
        for (int r = 0; r < 4; ++r) {
            Op[(size_t)(ct * 16 + g * 4 + r) * NPTS + qq] = __float2bfloat16(oacc[0][ct][r]);
            Op[(size_t)(ct * 16 + g * 4 + r) * NPTS + qq + 16] = __float2bfloat16(oacc[1][ct][r]);
        }
}

// ---------------------------------------------------------------------------
// K3: combine KSPLIT partials + normalize -> Xn bf16 (transposed), MFMA proj,
// bias, xaS f32; frames via float4 LDS reads + LDS-staged map_w.
// ---------------------------------------------------------------------------
__global__ __launch_bounds__(256) void proj_frames(const __hip_bfloat16* __restrict__ OTb,
                                                   const float* __restrict__ Lp,
                                                   const __hip_bfloat16* __restrict__ Wb,
                                                   const float* __restrict__ proj_b,
                                                   const float* __restrict__ map_w,
                                                   const float* __restrict__ map_b,
                                                   float* __restrict__ out,
                                                   float* __restrict__ frames0) {
    const int bh = blockIdx.y, b = bh >> 2, h = bh & 3;
    const int n0 = blockIdx.x * 64;
    const int cf0 = (b * 2 + 0) * 4 + h;
    const int cf1 = (b * 2 + 1) * 4 + h;

    __shared__ __align__(16) unsigned short Xn[64][72];  // [n][c] bf16
    __shared__ float xaS[64][68];                        // [n][j]
    __shared__ float mw[3][64];                          // map_w staged

    const int t = threadIdx.x;
    const int lane = t & 63, w = t >> 6;
    const int tx = t & 15, ty = t >> 4;
    const int l15 = lane & 15, g = (lane >> 4) & 3;
    const int nc = n0 + tx * 4;

    if (t < 192) mw[t >> 6][t & 63] = map_w[t];

    float4 L0 = make_float4(0.f, 0.f, 0.f, 0.f), L1 = L0;
#pragma unroll
    for (int s = 0; s < KSPLIT; ++s) {
        float4 a = *(const float4*)&Lp[(size_t)(s * 16 + cf0) * NPTS + nc];
        L0.x += a.x; L0.y += a.y; L0.z += a.z; L0.w += a.w;
        float4 c = *(const float4*)&Lp[(size_t)(s * 16 + cf1) * NPTS + nc];
        L1.x += c.x; L1.y += c.y; L1.z += c.z; L1.w += c.w;
    }
    float4 inv0 = make_float4(1.f / L0.x, 1.f / L0.y, 1.f / L0.z, 1.f / L0.w);
    float4 inv1 = make_float4(1.f / L1.x, 1.f / L1.y, 1.f / L1.z, 1.f / L1.w);

    for (int r = 0; r < 4; ++r) {
        int row = ty + 16 * r, col = tx * 4;   // row = c, col = n_local
        float x0 = 0.f, x1 = 0.f, x2 = 0.f, x3 = 0.f;
        float y0 = 0.f, y1 = 0.f, y2 = 0.f, y3 = 0.f;
#pragma unroll
        for (int s = 0; s < KSPLIT; ++s) {
            ushort4 u0 = *(const ushort4*)&OTb[((size_t)(s * 16 + cf0) * 64 + row) * NPTS + n0 + col];
            ushort4 u1 = *(const ushort4*)&OTb[((size_t)(s * 16 + cf1) * 64 + row) * NPTS + n0 + col];
            x0 += b2f(u0.x); x1 += b2f(u0.y); x2 += b2f(u0.z); x3 += b2f(u0.w);
            y0 += b2f(u1.x); y1 += b2f(u1.y); y2 += b2f(u1.z); y3 += b2f(u1.w);
        }
        Xn[col + 0][row] = __bfloat16_as_ushort(__float2bfloat16(x0 * inv0.x + y0 * inv1.x));
        Xn[col + 1][row] = __bfloat16_as_ushort(__float2bfloat16(x1 * inv0.y + y1 * inv1.y));
        Xn[col + 2][row] = __bfloat16_as_ushort(__float2bfloat16(x2 * inv0.z + y2 * inv1.z));
        Xn[col + 3][row] = __bfloat16_as_ushort(__float2bfloat16(x3 * inv0.w + y3 * inv1.w));
    }
    __syncthreads();

    {
        const __hip_bfloat16* wp = Wb + (size_t)(w * 16 + l15) * 64 + g * 8;
        bf16x8 wf0 = *(const bf16x8*)(wp);
        bf16x8 wf1 = *(const bf16x8*)(wp + 32);
        float pbias[4];
#pragma unroll
        for (int r = 0; r < 4; ++r) pbias[r] = proj_b[w * 16 + g * 4 + r];
#pragma unroll
        for (int nt = 0; nt < 4; ++nt) {
            bf16x8 xf0 = *(const bf16x8*)&Xn[nt * 16 + l15][g * 8];
            bf16x8 xf1 = *(const bf16x8*)&Xn[nt * 16 + l15][g * 8 + 32];
            f32x4 d = (f32x4){0.f, 0.f, 0.f, 0.f};
            d = __builtin_amdgcn_mfma_f32_16x16x32_bf16(wf0, xf0, d, 0, 0, 0);
            d = __builtin_amdgcn_mfma_f32_16x16x32_bf16(wf1, xf1, d, 0, 0, 0);
            float4 v = make_float4(d[0] + pbias[0], d[1] + pbias[1],
                                   d[2] + pbias[2], d[3] + pbias[3]);
            *(float4*)&xaS[nt * 16 + l15][w * 16 + g * 4] = v;
        }
    }
    __syncthreads();

    if (h >= 1) {
        float* __restrict__ xa_out = out + (size_t)(b * 3 + h - 1) * NPTS * 64;
        for (int r = 0; r < 4; ++r) {
            int n = ty + 16 * r;
            float4 v = *(const float4*)&xaS[n][tx * 4];
            *(float4*)&xa_out[(size_t)(n0 + n) * 64 + tx * 4] = v;
        }
    }

    if (t < 192) {
        int r = t / 3, j = t % 3;
        float s = map_b[j];
#pragma unroll
        for (int c4 = 0; c4 < 16; ++c4) {
            float4 xv = *(const float4*)&xaS[r][c4 * 4];
            float4 wv = *(const float4*)&mw[j][c4 * 4];
            s += xv.x * wv.x + xv.y * wv.y + xv.z * wv.z + xv.w * wv.w;
        }
        int n = n0 + r;
        if (h == 0) frames0[((size_t)b * NPTS + n) * 3 + j] = s;
        else        out[786432 + ((size_t)(b * 3 + h - 1) * NPTS + n) * 3 + j] = s;
    }
}

// ---------------------------------------------------------------------------
// K4a: chamfer partial mins -> device-scope atomicMin on monotonic-uint.
// grid (NPTS/256, NJC, 4); z = dir*2 + b.  min is associative => deterministic.
// ---------------------------------------------------------------------------
__global__ __launch_bounds__(256) void chamfer_partial(const float* __restrict__ pc1,
                                                       const float* __restrict__ frames0,
                                                       unsigned* __restrict__ minsU) {
    const int z = blockIdx.z;          // dir*2 + b
    const int dir = z >> 1, b = z & 1;
    const int i = blockIdx.x * 256 + threadIdx.x;
    const int j0 = blockIdx.y * JCH;
    const float* __restrict__ px = pc1 + (size_t)b * 3 * NPTS;
    const float* __restrict__ fr = frames0 + (size_t)b * NPTS * 3;

    __shared__ float4 sj[JCH];
    if (threadIdx.x < JCH) {
        int jj = j0 + threadIdx.x;
        float bx = px[jj], by = px[NPTS + jj], bz = px[2 * NPTS + jj];
        if (dir == 1) { bx += fr[jj * 3]; by += fr[jj * 3 + 1]; bz += fr[jj * 3 + 2]; }
        sj[threadIdx.x] = make_float4(bx, by, bz, bx * bx + by * by + bz * bz);
    }
    float ax = px[i], ay = px[NPTS + i], az = px[2 * NPTS + i];
    if (dir == 0) { ax += fr[i * 3]; ay += fr[i * 3 + 1]; az += fr[i * 3 + 2]; }
    const float a2 = ax * ax + ay * ay + az * az;
    __syncthreads();

    float best = 1e30f;
#pragma unroll 4
    for (int k = 0; k < JCH; ++k) {
        float4 p = sj[k];
        float d = a2 + p.w - 2.0f * (ax * p.x + ay * p.y + az * p.z);
        best = fminf(best, d);
    }
    atomicMin(&minsU[(size_t)z * NPTS + i], f2mono(best));
}

// ---------------------------------------------------------------------------
// K4b (fused): read final mins + per-block sum; LAST block (device-scope
// ticket) sums the 32 block sums in fixed order -> loss.
// ---------------------------------------------------------------------------
__global__ __launch_bounds__(256) void chamfer_minsum(const unsigned* __restrict__ minsU,
                                                      double* __restrict__ sums,
                                                      unsigned* __restrict__ counter,
                                                      float* __restrict__ loss_out) {
    const int gid = blockIdx.x * 256 + threadIdx.x;
    float best = mono2f(minsU[gid]);
    __shared__ double sm[256];
    sm[threadIdx.x] = (double)best;
    __syncthreads();
    for (int off = 128; off > 0; off >>= 1) {
        if (threadIdx.x < off) sm[threadIdx.x] += sm[threadIdx.x + off];
        __syncthreads();
    }
    if (threadIdx.x == 0) {
        sums[blockIdx.x] = sm[0];
        __threadfence();                            // release sums device-wide
        unsigned prev = atomicAdd(counter, 1u);     // device-scope arrival
        if (prev == 31u) {
            __threadfence();                        // acquire others' sums
            double s = 0.0;
            for (int k = 0; k < 32; ++k) s += sums[k];
            loss_out[0] = (float)(s / 4096.0);
            *counter = 0;
        }
    }
}

// ---------------------------------------------------------------------------
extern "C" void kernel_launch(void* const* d_in, const int* in_sizes, int n_in,
                              void* d_out, int out_size, void* d_ws, size_t ws_size,
                              hipStream_t stream) {
    const float* xs     = (const float*)d_in[0];
    const float* pc1    = (const float*)d_in[1];
    // d_in[2] = pc2 (unused by reference)
    const float* gamma  = (const float*)d_in[3];
    const float* beta   = (const float*)d_in[4];
    const float* q_w    = (const float*)d_in[5];
    const float* kv_w   = (const float*)d_in[6];
    const float* proj_w = (const float*)d_in[7];
    const float* proj_b = (const float*)d_in[8];
    const float* map_w  = (const float*)d_in[9];
    const float* map_b  = (const float*)d_in[10];
    float* out = (float*)d_out;

    char* ws = (char*)d_ws;
    __hip_bfloat16* Qg  = (__hip_bfloat16*)(ws);              // 4 MiB
    __hip_bfloat16* Kg  = (__hip_bfloat16*)(ws + 4194304);    // 4 MiB
    __hip_bfloat16* Vtg = (__hip_bfloat16*)(ws + 8388608);    // 4 MiB
    __hip_bfloat16* OTb = (__hip_bfloat16*)(ws + 12582912);   // 32 MiB
    __hip_bfloat16* Wpb = (__hip_bfloat16*)(ws + 46137344);   // 96 KiB
    __hip_bfloat16* xT  = (__hip_bfloat16*)(ws + 46235648);   // 2 MiB
    float* frames0 = (float*)(ws + 48332800);                 // 48 KiB
    unsigned* minsU = (unsigned*)(ws + 48381952);             // 32 KiB
    double* sums   = (double*)(ws + 48906240);                // 256 B
    float* Lp      = (float*)(ws + 48906496);                 // 1 MiB
    __hip_bfloat16* Wb  = (__hip_bfloat16*)(ws + 49955072);   // 8 KiB
    unsigned* counter   = (unsigned*)(ws + 49963264);         // 4 B

    hipLaunchKernelGGL(prep_all, dim3(260), dim3(256), 0, stream,
                       xs, gamma, beta, q_w, kv_w, proj_w, xT, Wpb, Wb, minsU, counter);
    hipLaunchKernelGGL(qkv_mfma, dim3(32, 12, 4), dim3(256), 0, stream,
                       xT, Wpb, Qg, Kg, Vtg);
    hipLaunchKernelGGL(attn_mfma, dim3(16, 16, KSPLIT), dim3(256), 0, stream,
                       Qg, Kg, Vtg, OTb, Lp);
    hipLaunchKernelGGL(proj_frames, dim3(32, 8), dim3(256), 0, stream,
                       OTb, Lp, Wb, proj_b, map_w, map_b, out, frames0);
    hipLaunchKernelGGL(chamfer_partial, dim3(NPTS / 256, NJC, 4), dim3(256), 0, stream,
                       pc1, frames0, minsU);
    hipLaunchKernelGGL(chamfer_minsum, dim3(32), dim3(256), 0, stream,
                       minsU, sums, counter, out + 823296);
}